// Round 4
// baseline (27.805 us; speedup 1.0000x reference)
//
#include <hip/hip_runtime.h>

// Problem constants (match reference setup_inputs)
#define BATCH 2
#define NPART 4096
#define TI 256                 // i-particles per block (1 per thread)
#define JSEGS 64               // -> 64*16*2 = 2048 blocks (8/CU, 8 waves/SIMD)
#define SEG (NPART / JSEGS)    // 64 j-particles staged in LDS per block
#define PLANE (BATCH * NPART)  // 8192 floats per (jseg,c) partial plane

typedef float v2f __attribute__((ext_vector_type(2)));

// Inner loop: 2 pairs per iteration in packed-f32 registers.
// One v_rcp per 2 pairs: inv(a),inv(b) = rcp(a*b) * {b,a}.
// MASKED=true only for blocks whose j-range can contain j==i.
template <bool MASKED>
__device__ inline void lj_inner(const v2f* xs, const v2f* ys, const v2f* zs,
                                float qx, float qy, float qz,
                                float& Fx, float& Fy, float& Fz) {
    v2f fx = (v2f)0.0f, fy = (v2f)0.0f, fz = (v2f)0.0f;

    #pragma unroll 8
    for (int jj = 0; jj < SEG / 2; ++jj) {
        const v2f dx = (v2f)qx - xs[jj];
        const v2f dy = (v2f)qy - ys[jj];
        const v2f dz = (v2f)qz - zs[jj];
        v2f r2 = dx * dx;
        r2 = __builtin_elementwise_fma(dy, dy, r2);
        r2 = __builtin_elementwise_fma(dz, dz, r2);

        // safe_r2: only the diagonal blocks can see r2==0 (i==j)
        v2f r2s = r2;
        if (MASKED) {
            r2s.x = (r2.x > 0.0f) ? r2.x : 1.0f;
            r2s.y = (r2.y > 0.0f) ? r2.y : 1.0f;
        }
        // combined reciprocal: 1 transcendental per 2 pairs
        const float rc = __builtin_amdgcn_rcpf(r2s.x * r2s.y);
        v2f inv = (v2f)rc * __builtin_shufflevector(r2s, r2s, 1, 0);
        if (MASKED) {
            inv.x = (r2.x > 0.0f) ? inv.x : 0.0f;
            inv.y = (r2.y > 0.0f) ? inv.y : 0.0f;
        }
        const v2f inv2 = inv * inv;
        const v2f s6 = inv2 * inv;                                    // sigma = 1
        const v2f c1 = __builtin_elementwise_fma((v2f)48.0f, s6, (v2f)(-24.0f));
        const v2f coeff = (inv * s6) * c1;   // 24*inv*s6*(2*s6-1)
        fx = __builtin_elementwise_fma(coeff, dx, fx);
        fy = __builtin_elementwise_fma(coeff, dy, fy);
        fz = __builtin_elementwise_fma(coeff, dz, fz);
    }

    Fx = fx.x + fx.y;
    Fy = fy.x + fy.y;
    Fz = fz.x + fz.y;
}

// Grid: (JSEGS, NPART/TI, BATCH), block TI=256.
// Writes per-jseg partial forces to ws (no atomics, no pre-zeroing needed):
//   ws[(jseg*3 + c) * PLANE + b*NPART + i]   -- coalesced dword stores
__global__ __launch_bounds__(256) void lj_kernel(const float* __restrict__ q,
                                                 float* __restrict__ ws) {
    __shared__ float qsx[SEG], qsy[SEG], qsz[SEG];

    const int jseg  = blockIdx.x;
    const int itile = blockIdx.y;
    const int b     = blockIdx.z;

    const float* qb = q + (size_t)b * NPART * 3;

    if (threadIdx.x < SEG) {
        const int k = threadIdx.x;
        const int jb = jseg * SEG * 3 + 3 * k;
        qsx[k] = qb[jb + 0];
        qsy[k] = qb[jb + 1];
        qsz[k] = qb[jb + 2];
    }
    __syncthreads();

    const int i = itile * TI + threadIdx.x;
    const float qx = qb[i * 3 + 0];
    const float qy = qb[i * 3 + 1];
    const float qz = qb[i * 3 + 2];

    float Fx, Fy, Fz;
    // Diagonal possible iff j-range overlaps i-range (TI/SEG = 4)
    const bool diag = (jseg >> 2) == itile;
    if (diag) {
        lj_inner<true >((const v2f*)qsx, (const v2f*)qsy, (const v2f*)qsz,
                        qx, qy, qz, Fx, Fy, Fz);
    } else {
        lj_inner<false>((const v2f*)qsx, (const v2f*)qsy, (const v2f*)qsz,
                        qx, qy, qz, Fx, Fy, Fz);
    }

    const size_t base = (size_t)(jseg * 3) * PLANE + (size_t)b * NPART + i;
    ws[base]             = Fx;
    ws[base + PLANE]     = Fy;
    ws[base + 2 * PLANE] = Fz;
}

// Reduce 64 partials per dp element; fuse dq = p/m.
// o in [0, 24576) indexes (c, b, i) planes; dp is [b][i][c].
__global__ __launch_bounds__(256) void reduce_kernel(const float* __restrict__ ws,
                                                     const float* __restrict__ p,
                                                     const float* __restrict__ m,
                                                     float* __restrict__ dq,
                                                     float* __restrict__ dp) {
    const int o  = blockIdx.x * 256 + threadIdx.x;   // 24576 threads
    const int c  = o >> 13;          // / PLANE
    const int bi = o & (PLANE - 1);  // b*NPART + i

    float s0 = 0.0f, s1 = 0.0f;
    #pragma unroll 16
    for (int js = 0; js < JSEGS; js += 2) {
        s0 += ws[(size_t)(js * 3 + c) * PLANE + bi];
        s1 += ws[(size_t)((js + 1) * 3 + c) * PLANE + bi];
    }
    dp[(size_t)bi * 3 + c] = s0 + s1;

    // dq = p/m for flat element o (exact IEEE div, only 24576 of them)
    dq[o] = p[o] / m[o / 3];
}

extern "C" void kernel_launch(void* const* d_in, const int* in_sizes, int n_in,
                              void* d_out, int out_size, void* d_ws, size_t ws_size,
                              hipStream_t stream) {
    const float* q = (const float*)d_in[0];
    const float* p = (const float*)d_in[1];
    const float* m = (const float*)d_in[2];
    // d_in[3] = t, unused by the reference outputs

    const int n_elem = BATCH * NPART * 3;   // 24576 per output tensor
    float* dq_out = (float*)d_out;          // first output: dq
    float* dp_out = (float*)d_out + n_elem; // second output: dp
    float* ws     = (float*)d_ws;           // 64*3*8192 floats = 6.3 MB partials

    dim3 grid(JSEGS, NPART / TI, BATCH);
    lj_kernel<<<grid, TI, 0, stream>>>(q, ws);

    reduce_kernel<<<n_elem / 256, 256, 0, stream>>>(ws, p, m, dq_out, dp_out);
}